// Round 8
// baseline (322.588 us; speedup 1.0000x reference)
//
#include <hip/hip_runtime.h>
#include <hip/hip_bf16.h>

typedef __bf16 bf16x8 __attribute__((ext_vector_type(8)));
typedef float  f32x4  __attribute__((ext_vector_type(4)));

#define N_TOT   16384
#define K_TOT   16384
#define HALF_M  ((size_t)128 * 16384)
#define BN      128
#define BK      32
#define KSPLIT  4
#define KQ_LEN  (K_TOT / KSPLIT)      // 4096
#define NQSTEPS (KQ_LEN / BK)         // 128
#define OUT_ELEMS ((size_t)256 * 16384)

__device__ __forceinline__ unsigned short f2bf(float f) {
    __hip_bfloat16 h = __float2bfloat16(f);
    return __builtin_bit_cast(unsigned short, h);
}

// 64-B rows (BK=32 bf16), 16-B granules (4/row): XOR granule with (row>>1)&3.
// Verified <=2-way (free) on frag-read, A-stage-write, B-stage-write patterns.
__device__ __forceinline__ int swz64(int row, int g) {
    return row * 64 + (((g ^ ((row >> 1) & 3)) & 3) << 4);
}

// One-time T = concat(x0,x1) fp32 -> bf16 into workspace (linear row-major).
__global__ void cvtT_kernel(const float* __restrict__ x0,
                            const float* __restrict__ x1,
                            unsigned short* __restrict__ wsT) {
    size_t i = (size_t)blockIdx.x * blockDim.x + threadIdx.x;  // 0..524287
    size_t e = i * 8;
    const float* src = (e < HALF_M) ? (x0 + e) : (x1 + (e - HALF_M));
    float4 a = ((const float4*)src)[0];
    float4 b = ((const float4*)src)[1];
    union { unsigned short u[8]; uint4 v; } o;
    o.u[0] = f2bf(a.x); o.u[1] = f2bf(a.y); o.u[2] = f2bf(a.z); o.u[3] = f2bf(a.w);
    o.u[4] = f2bf(b.x); o.u[5] = f2bf(b.y); o.u[6] = f2bf(b.z); o.u[7] = f2bf(b.w);
    ((uint4*)wsT)[i] = o.v;
}

// out += p0 + p1 + p2 (fixed order -> deterministic)
__global__ void combine_kernel(float* __restrict__ out,
                               const float* __restrict__ p0,
                               const float* __restrict__ p1,
                               const float* __restrict__ p2) {
    const size_t n4 = OUT_ELEMS / 4;
    size_t i = (size_t)blockIdx.x * blockDim.x + threadIdx.x;
    for (; i < n4; i += (size_t)gridDim.x * blockDim.x) {
        float4 o = ((const float4*)out)[i];
        float4 a = ((const float4*)p0)[i];
        float4 b = ((const float4*)p1)[i];
        float4 c = ((const float4*)p2)[i];
        o.x += a.x + b.x + c.x;  o.y += a.y + b.y + c.y;
        o.z += a.z + b.z + c.z;  o.w += a.w + b.w + c.w;
        ((float4*)out)[i] = o;
    }
}

// ---- depth-2 static prefetch sets ----
// A: thread covers 32 B (granules 2*pa, 2*pa+1) of one row; W: 8 f32.
#define ISSUEW(S, k0) do {                                                    \
    const uint4* _p = (const uint4*)(arow_w + (k0));                          \
    w##S##_0 = _p[0]; w##S##_1 = _p[1];                                       \
    const float4* _q = (const float4*)(brow + (k0));                          \
    wb##S##_0 = _q[0]; wb##S##_1 = _q[1];                                     \
} while (0)

#define STAGEW(S, Ab, Bb) do {                                                \
    *(uint4*)((Ab) + aw0) = w##S##_0;                                         \
    *(uint4*)((Ab) + aw1) = w##S##_1;                                         \
    union { unsigned short u[8]; uint4 v; } _tb;                              \
    _tb.u[0]=f2bf(wb##S##_0.x); _tb.u[1]=f2bf(wb##S##_0.y);                   \
    _tb.u[2]=f2bf(wb##S##_0.z); _tb.u[3]=f2bf(wb##S##_0.w);                   \
    _tb.u[4]=f2bf(wb##S##_1.x); _tb.u[5]=f2bf(wb##S##_1.y);                   \
    _tb.u[6]=f2bf(wb##S##_1.z); _tb.u[7]=f2bf(wb##S##_1.w);                   \
    *(uint4*)((Bb) + bw) = _tb.v;                                             \
} while (0)

// 8 waves as 2M x 4N over 256M x 128N: wave owns 128M x 32N.
// 8 A-reads + 2 B-reads + 16 MFMA per step; mf offsets fold to immediates.
#define COMPUTE(Ab, Bb) do {                                                  \
    bf16x8 _vb0 = *(const bf16x8*)((Bb) + boff0);                             \
    bf16x8 _vb1 = *(const bf16x8*)((Bb) + boff0 + 1024);                      \
    bf16x8 _va;                                                               \
    _va = *(const bf16x8*)((Ab) + aoff0 + 0*1024);                            \
    accA0 = __builtin_amdgcn_mfma_f32_16x16x32_bf16(_va, _vb0, accA0, 0,0,0); \
    accB0 = __builtin_amdgcn_mfma_f32_16x16x32_bf16(_va, _vb1, accB0, 0,0,0); \
    _va = *(const bf16x8*)((Ab) + aoff0 + 1*1024);                            \
    accA1 = __builtin_amdgcn_mfma_f32_16x16x32_bf16(_va, _vb0, accA1, 0,0,0); \
    accB1 = __builtin_amdgcn_mfma_f32_16x16x32_bf16(_va, _vb1, accB1, 0,0,0); \
    _va = *(const bf16x8*)((Ab) + aoff0 + 2*1024);                            \
    accA2 = __builtin_amdgcn_mfma_f32_16x16x32_bf16(_va, _vb0, accA2, 0,0,0); \
    accB2 = __builtin_amdgcn_mfma_f32_16x16x32_bf16(_va, _vb1, accB2, 0,0,0); \
    _va = *(const bf16x8*)((Ab) + aoff0 + 3*1024);                            \
    accA3 = __builtin_amdgcn_mfma_f32_16x16x32_bf16(_va, _vb0, accA3, 0,0,0); \
    accB3 = __builtin_amdgcn_mfma_f32_16x16x32_bf16(_va, _vb1, accB3, 0,0,0); \
    _va = *(const bf16x8*)((Ab) + aoff0 + 4*1024);                            \
    accA4 = __builtin_amdgcn_mfma_f32_16x16x32_bf16(_va, _vb0, accA4, 0,0,0); \
    accB4 = __builtin_amdgcn_mfma_f32_16x16x32_bf16(_va, _vb1, accB4, 0,0,0); \
    _va = *(const bf16x8*)((Ab) + aoff0 + 5*1024);                            \
    accA5 = __builtin_amdgcn_mfma_f32_16x16x32_bf16(_va, _vb0, accA5, 0,0,0); \
    accB5 = __builtin_amdgcn_mfma_f32_16x16x32_bf16(_va, _vb1, accB5, 0,0,0); \
    _va = *(const bf16x8*)((Ab) + aoff0 + 6*1024);                            \
    accA6 = __builtin_amdgcn_mfma_f32_16x16x32_bf16(_va, _vb0, accA6, 0,0,0); \
    accB6 = __builtin_amdgcn_mfma_f32_16x16x32_bf16(_va, _vb1, accB6, 0,0,0); \
    _va = *(const bf16x8*)((Ab) + aoff0 + 7*1024);                            \
    accA7 = __builtin_amdgcn_mfma_f32_16x16x32_bf16(_va, _vb0, accA7, 0,0,0); \
    accB7 = __builtin_amdgcn_mfma_f32_16x16x32_bf16(_va, _vb1, accB7, 0,0,0); \
} while (0)

#define SYNC do {                                                             \
    asm volatile("s_waitcnt lgkmcnt(0)" ::: "memory");                        \
    __builtin_amdgcn_s_barrier();                                             \
    __builtin_amdgcn_sched_barrier(0);                                        \
} while (0)

// GEMM: grid 512 = 128 nstrips x 4 kq (kq=bid>>7, R5 mapping). 512 threads,
// 48 KiB LDS -> 2 blocks/CU co-resident: when one block stalls on its W
// vmcnt, the other block's waves keep the CU busy (m114 wave-level overlap).
__global__ __launch_bounds__(512, 4)
void gemm_ws(const float* __restrict__ W, const float* __restrict__ bias,
             const unsigned short* __restrict__ wsT,
             float* __restrict__ out, float* __restrict__ wsP)
{
    __shared__ uint4 smem_[(2 * 16384 + 2 * 8192) / 16];   // 48 KiB
    char* const sm = (char*)smem_;
    char* const A0 = sm;                       // A: 256 rows x 64 B
    char* const A1 = sm + 16384;
    char* const B0 = sm + 32768;               // B: 128 rows x 64 B
    char* const B1 = sm + 32768 + 8192;

    const int tid  = threadIdx.x;
    const int lane = tid & 63;
    const int wave = tid >> 6;                 // 0..7
    const int wm = wave >> 2;                  // 0..1 (128 M rows)
    const int wn = wave & 3;                   // 0..3 (32 N cols)
    const int bid    = blockIdx.x;
    const int kq     = bid >> 7;               // 0..3
    const int nstrip = bid & 127;
    const int n0     = nstrip * BN;
    const int kbase  = kq * KQ_LEN;

    // staging geometry
    const int ra = tid >> 1;                   // A row 0..255
    const int pa = tid & 1;                    // which 32-B half of 64-B row
    const int rb = tid >> 2;                   // B row 0..127
    const int gb = tid & 3;                    // 16-B granule (8 f32 source)

    const unsigned short* arow_w = wsT + (size_t)ra * K_TOT + kbase + pa * 16;
    const float* brow = W + (size_t)(n0 + rb) * K_TOT + kbase + gb * 8;

    const int aw0 = swz64(ra, 2 * pa);
    const int aw1 = swz64(ra, 2 * pa + 1);
    const int bw  = swz64(rb, gb);

    // frag-read offsets; (row>>1)&3 is mf/nf-independent -> mf*1024 immediates
    const int aoff0 = swz64(wm * 128 + (lane & 15), lane >> 4);
    const int boff0 = swz64(wn * 32 + (lane & 15), lane >> 4);

    f32x4 accA0={0.f,0.f,0.f,0.f}, accA1={0.f,0.f,0.f,0.f};
    f32x4 accA2={0.f,0.f,0.f,0.f}, accA3={0.f,0.f,0.f,0.f};
    f32x4 accA4={0.f,0.f,0.f,0.f}, accA5={0.f,0.f,0.f,0.f};
    f32x4 accA6={0.f,0.f,0.f,0.f}, accA7={0.f,0.f,0.f,0.f};
    f32x4 accB0={0.f,0.f,0.f,0.f}, accB1={0.f,0.f,0.f,0.f};
    f32x4 accB2={0.f,0.f,0.f,0.f}, accB3={0.f,0.f,0.f,0.f};
    f32x4 accB4={0.f,0.f,0.f,0.f}, accB5={0.f,0.f,0.f,0.f};
    f32x4 accB6={0.f,0.f,0.f,0.f}, accB7={0.f,0.f,0.f,0.f};

    uint4  w0_0, w0_1, w1_0, w1_1;
    float4 wb0_0, wb0_1, wb1_0, wb1_1;

    ISSUEW(0, 0);
    ISSUEW(1, BK);
    STAGEW(0, A0, B0);
    SYNC;

    for (int kt = 0; kt < NQSTEPS; kt += 2) {
        if (kt + 2 < NQSTEPS) ISSUEW(0, (kt + 2) * BK);
        COMPUTE(A0, B0);
        STAGEW(1, A1, B1);
        SYNC;
        if (kt + 3 < NQSTEPS) ISSUEW(1, (kt + 3) * BK);
        COMPUTE(A1, B1);
        if (kt + 2 < NQSTEPS) STAGEW(0, A0, B0);
        SYNC;
    }

    // epilogue: kq==0 writes bias+acc to out; kq>0 writes acc to partial buf.
    float* const dst = (kq == 0) ? out : (wsP + (size_t)(kq - 1) * OUT_ELEMS);
    #pragma unroll
    for (int nf = 0; nf < 2; ++nf) {
        const int col = n0 + wn * 32 + nf * 16 + (lane & 15);
        const float bv = (kq == 0) ? bias[col] : 0.f;
        #pragma unroll
        for (int mf = 0; mf < 8; ++mf) {
            const f32x4 a = (nf == 0)
                ? (mf==0?accA0:mf==1?accA1:mf==2?accA2:mf==3?accA3:
                   mf==4?accA4:mf==5?accA5:mf==6?accA6:accA7)
                : (mf==0?accB0:mf==1?accB1:mf==2?accB2:mf==3?accB3:
                   mf==4?accB4:mf==5?accB5:mf==6?accB6:accB7);
            #pragma unroll
            for (int j = 0; j < 4; ++j) {
                int r = wm * 128 + mf * 16 + (lane >> 4) * 4 + j;
                float v = a[j] + bv;
                float* o = (r < 128) ? (dst + (size_t)r * N_TOT + col)
                                     : (dst + HALF_M + (size_t)(r - 128) * N_TOT + col);
                *o = v;
            }
        }
    }
}

extern "C" void kernel_launch(void* const* d_in, const int* in_sizes, int n_in,
                              void* d_out, int out_size, void* d_ws, size_t ws_size,
                              hipStream_t stream) {
    const float* x0 = (const float*)d_in[0];
    const float* x1 = (const float*)d_in[1];
    const float* W  = (const float*)d_in[2];
    const float* b  = (const float*)d_in[3];
    float* out = (float*)d_out;

    const size_t wsT_bytes = (size_t)256 * 16384 * sizeof(unsigned short);  // 8.4 MB

    unsigned short* wsT = (unsigned short*)d_ws;
    float* wsP = (float*)((char*)d_ws + wsT_bytes);

    cvtT_kernel<<<2048, 256, 0, stream>>>(x0, x1, wsT);
    gemm_ws<<<512, 512, 0, stream>>>(W, b, wsT, out, wsP);
    combine_kernel<<<2048, 256, 0, stream>>>(out, wsP, wsP + OUT_ELEMS,
                                             wsP + 2 * OUT_ELEMS);
}